// Round 5
// baseline (1199.862 us; speedup 1.0000x reference)
//
#include <hip/hip_runtime.h>
#include <stddef.h>
#include <stdint.h>

// Problem constants
#define IN_F      1024
#define SHORTLIST 4000
#define C1_LO     4000
#define C1_HI     20000
#define C2_HI     50257
#define NROWS     8192

// Workspace layout (4-byte words) -- bookkeeping region
#define WS_CNT1   0
#define WS_CNT2   1
#define WS_LOSS   2
#define WS_RL1    4
#define WS_RL2    (4 + 8192)
#define WS_SEH    (4 + 2*8192)            // sumexp_head[8192]
#define WS_SET    (WS_SEH + 8192)         // sumexp_tail[8192]
#define WS_CAP    (WS_SET + 8192)         // captured target/gather logit[8192]
#define WS_WORDS  (WS_CAP + 8192)         // ~164 KB

// bf16 scratch region (bytes)
#define WBF_OFF   (262144)                              // 256 KB aligned
#define XBF_OFF   (WBF_OFF + 103219200)                 // padded/aligned
#define XBF_BYTES ((size_t)NROWS * IN_F * 2)            // 16,777,216
#define WS_NEEDED (XBF_OFF + XBF_BYTES)

// Fused-GEMM grid: jobs concatenated, row-strip (of 128) fastest for B L2 reuse.
// Each block covers 4 column-tiles of 128 => 512 classes.
#define GRID_HEAD 512          // 64 rowstrips x 8  cgroups (4000 cls -> 32 strips)
#define GRID_T1   2048         // 64 rowstrips x 32 cgroups (16000 -> 125 strips)
#define GRID_T2   3840         // 64 rowstrips x 60 cgroups (30257 -> 237 strips)
#define GRID_ALL  (GRID_HEAD + GRID_T1 + GRID_T2)

typedef float          f32x4  __attribute__((ext_vector_type(4)));
typedef __bf16         bf16x8 __attribute__((ext_vector_type(8)));
typedef unsigned short us8    __attribute__((ext_vector_type(8)));
typedef unsigned short ushort_t;

__device__ __forceinline__ unsigned short f2bf(float f) {
    unsigned int u = __float_as_uint(f);
    u += 0x7fffu + ((u >> 16) & 1u);   // round-to-nearest-even
    return (unsigned short)(u >> 16);
}

__device__ __forceinline__ void gl_lds16(const void* g, void* l) {
    __builtin_amdgcn_global_load_lds(
        (const __attribute__((address_space(1))) void*)g,
        (__attribute__((address_space(3))) void*)l, 16, 0, 0);
}

#define VMCNT4() asm volatile("s_waitcnt vmcnt(4)" ::: "memory")
#define VMCNT0() asm volatile("s_waitcnt vmcnt(0)" ::: "memory")
#define BAR()    __builtin_amdgcn_s_barrier()

// ---------------------------------------------------------------------------
__global__ void init_ws_k(int* __restrict__ ws) {
    int i = blockIdx.x * 256 + threadIdx.x;
    if (i < WS_WORDS) {
        int v = (i >= WS_RL1 && i < WS_RL1 + 2*8192) ? -1 : 0;
        ws[i] = v;
    }
}

__global__ void compact_rows_k(const int* __restrict__ target, int* __restrict__ ws) {
    int row = blockIdx.x * 256 + threadIdx.x;
    if (row >= NROWS) return;
    int tg = target[row];
    if (tg >= C1_LO) {
        if (tg < C1_HI) {
            int p = atomicAdd(&ws[WS_CNT1], 1);
            ws[WS_RL1 + p] = row;
        } else {
            int p = atomicAdd(&ws[WS_CNT2], 1);
            ws[WS_RL2 + p] = row;
        }
    }
}

// ---------------------------------------------------------------------------
// fp32 -> bf16 bulk convert: weight then input in one dispatch
// ---------------------------------------------------------------------------
#define WCHUNKS ((C2_HI * IN_F) / 8)       // 6,432,896
#define XCHUNKS ((NROWS * IN_F) / 8)       // 1,048,576
__global__ void convert_bf16_k(const float* __restrict__ w_src,
                               ushort_t* __restrict__ w_dst,
                               const float* __restrict__ x_src,
                               ushort_t* __restrict__ x_dst) {
    int i = blockIdx.x * 256 + threadIdx.x;
    const float* p;
    ushort_t* d;
    if (i < WCHUNKS) { p = w_src + (size_t)i * 8; d = w_dst + (size_t)i * 8; }
    else {
        int j = i - WCHUNKS;
        if (j >= XCHUNKS) return;
        p = x_src + (size_t)j * 8; d = x_dst + (size_t)j * 8;
    }
    f32x4 x0 = *(const f32x4*)p;
    f32x4 x1 = *(const f32x4*)(p + 4);
    us8 o;
    o[0] = f2bf(x0[0]); o[1] = f2bf(x0[1]); o[2] = f2bf(x0[2]); o[3] = f2bf(x0[3]);
    o[4] = f2bf(x1[0]); o[5] = f2bf(x1[1]); o[6] = f2bf(x1[2]); o[7] = f2bf(x1[3]);
    *(us8*)d = o;
}

// ---------------------------------------------------------------------------
// FUSED bf16 GEMM + exp-sum + target capture, all 3 cluster jobs in one grid.
// 128x128 tile, gl_lds(16B) staging.
//
// T3/T4 pipeline (m201 discipline) at BK=32 with STATIC double buffers
// (As0/Bs0, As1/Bs1 -- named arrays, no runtime indexing; rule #20).
// Steady-state step:
//     STAGE(other, k_next)        // 4 gl_lds/wave, fire-and-forget
//     s_waitcnt vmcnt(4)          // retire CURRENT buffer's 4 (in-order),
//                                 // leave the 4 just-issued in flight
//     s_barrier                   // all waves certified current buffer
//     ds_read + 16 MFMA (current) // compiler-managed lgkmcnt
//     s_barrier                   // readers done -> buffer reusable
// vmcnt reaches 0 only at ctile prologue/tail -- prefetch survives barriers,
// which __syncthreads (vmcnt(0) drain) structurally forbids (the round-2 /
// m99/m100 null). LDS = 4 x 8KB + 2.8KB = 34.8KB -> keeps 3 blocks/CU.
//
// vmcnt ledger (per wave): prologue STAGE 4 -> VMCNT0 -> 0. Steady half-step:
// issue 4 (out=8) -> VMCNT4 retires exactly the 4 belonging to the buffer
// about to be read. Epilogue's capture[] stores are issued only at ctile end
// and drained by the next ctile's prologue VMCNT0, so they never perturb the
// steady-state count.
//
// SWIZZLE (fixed this round -- previous BK=32 draft was 4-way conflicted):
// LDS row stride 32 ushorts (16 words) => bank group = (r&1, slot) (8 groups
// of 4 banks). Slot function must make (r&1, slot) bijective in s&7 within a
// 16-lane ds_read phase: use f(r) = (r>>1)&3.
//   stage: lane l -> row t*16+(l>>2), slot l&3, global k-quarter
//          psw = (l&3) ^ ((l>>3)&3)       [= slot ^ f(row)]
//   read : row r, k-octet q -> slot q ^ ((s>>1)&3)   [(r>>1)&3 == (s>>1)&3]
// Same involution both sides (rule #21); 2 lanes/bank-group = free (m136).
// Fragment mapping (row<-s, k-octet<-q) and K-accumulation order (k=0,32,...)
// identical to the 1189us round-3 kernel => bit-identical numerics.
// ---------------------------------------------------------------------------
__launch_bounds__(256, 3)
__global__ void gemm_lse_fused_k(const ushort_t* __restrict__ Xbf,  // [NROWS][IN_F]
                                 const ushort_t* __restrict__ Wbf,  // [C2_HI][IN_F]
                                 const float* __restrict__ bias,
                                 const int*   __restrict__ target,
                                 int*   __restrict__ wsI,
                                 float* __restrict__ wsF)
{
    // ---- job decode (row-strip fastest within each job)
    const int bid = blockIdx.x;
    int rs, cg, cbase, C, cnt;
    const int* rowlist;           // null => identity
    float* sumexp;
    if (bid < GRID_HEAD) {
        rs = bid & 63; cg = bid >> 6;
        cbase = 0; C = SHORTLIST; rowlist = nullptr; cnt = NROWS;
        sumexp = wsF + WS_SEH;
    } else if (bid < GRID_HEAD + GRID_T1) {
        int b = bid - GRID_HEAD;
        rs = b & 63; cg = b >> 6;
        cbase = C1_LO; C = C1_HI - C1_LO; rowlist = wsI + WS_RL1; cnt = wsI[WS_CNT1];
        sumexp = wsF + WS_SET;
    } else {
        int b = bid - (GRID_HEAD + GRID_T1);
        rs = b & 63; cg = b >> 6;
        cbase = C1_HI; C = C2_HI - C1_HI; rowlist = wsI + WS_RL2; cnt = wsI[WS_CNT2];
        sumexp = wsF + WS_SET;
    }
    const int r0 = rs * 128;
    if (r0 >= cnt) return;
    float* capture = wsF + WS_CAP;

    __shared__ ushort_t As0[128 * 32];   // 8 KB each
    __shared__ ushort_t Bs0[128 * 32];
    __shared__ ushort_t As1[128 * 32];
    __shared__ ushort_t Bs1[128 * 32];
    __shared__ int   orig_s[128];
    __shared__ int   tgt_s[128];
    __shared__ float part[256];          // [wn][row] exp-sum accum across ctiles

    const int tid = threadIdx.x;
    part[tid] = 0.f;
    if (tid < 128) {
        int idx  = r0 + tid;
        int orig = (idx < cnt) ? (rowlist ? rowlist[idx] : idx) : -1;
        orig_s[tid] = orig;
        tgt_s[tid]  = (orig >= 0) ? target[orig] : -1;
    }
    __syncthreads();

    const int lane = tid & 63;
    const int wave = tid >> 6;
    const int wm = wave >> 1, wn = wave & 1;
    const int q = lane >> 4, s = lane & 15;

    // ---- staging setup: wave handles insts t = wave*2+i (i=0,1), each inst
    // covers rows t*16..t*16+15. lane l -> row t*16+(l>>2), LDS slot l&3;
    // source k-quarter pre-swizzled: psw = (l&3) ^ ((l>>3)&3).
    const int lrow = lane >> 2;                    // row within 16
    const int psw  = (lane & 3) ^ ((lane >> 3) & 3);
    const ushort_t* aptr[2];
    int tsl[2];                                     // wave-uniform LDS inst base
    int brow[2];
#pragma unroll
    for (int i = 0; i < 2; ++i) {
        int t  = wave * 2 + i;
        int rt = t * 16 + lrow;
        int orig = orig_s[rt]; if (orig < 0) orig = 0;          // safe addr; masked later
        aptr[i] = Xbf + (size_t)orig * IN_F + psw * 8;
        tsl[i]  = t * 512;                                      // 512 ushorts = 1KB
        brow[i] = rt;
    }

    // ---- fragment read offsets (ushort units): row*32 + (q^((s>>1)&3))*8
    int ar_off[4], br_off[4];
#pragma unroll
    for (int i = 0; i < 4; ++i) {
        ar_off[i] = (wm * 64 + i * 16 + s) * 32 + (q ^ ((s >> 1) & 3)) * 8;
        br_off[i] = (wn * 64 + i * 16 + s) * 32 + (q ^ ((s >> 1) & 3)) * 8;
    }

#define STAGE(AS, BS, K0) do {                                                 \
    _Pragma("unroll")                                                          \
    for (int i_ = 0; i_ < 2; ++i_) {                                           \
        gl_lds16(aptr[i_] + (K0), &AS[tsl[i_]]);                               \
        gl_lds16(bptr[i_] + (K0), &BS[tsl[i_]]);                               \
    }                                                                          \
} while (0)

#define MFMA_STEP(AS, BS) do {                                                 \
    bf16x8 av_[4], bv_[4];                                                     \
    _Pragma("unroll")                                                          \
    for (int i_ = 0; i_ < 4; ++i_) {                                           \
        av_[i_] = *(const bf16x8*)&AS[ar_off[i_]];                             \
        bv_[i_] = *(const bf16x8*)&BS[br_off[i_]];                             \
    }                                                                          \
    _Pragma("unroll")                                                          \
    for (int mi_ = 0; mi_ < 4; ++mi_)                                          \
        _Pragma("unroll")                                                      \
        for (int ni_ = 0; ni_ < 4; ++ni_)                                      \
            acc[mi_][ni_] = __builtin_amdgcn_mfma_f32_16x16x32_bf16(           \
                av_[mi_], bv_[ni_], acc[mi_][ni_], 0, 0, 0);                   \
} while (0)

    // ---- loop over 4 column-tiles
    for (int ct = 0; ct < 4; ++ct) {
        const int c0 = (cg * 4 + ct) * 128;
        if (c0 >= C) break;                     // block-uniform

        const ushort_t* bptr[2];
#pragma unroll
        for (int i = 0; i < 2; ++i) {
            int c = c0 + brow[i]; if (c >= C) c = C - 1;    // clamp; masked later
            bptr[i] = Wbf + (size_t)(cbase + c) * IN_F + psw * 8;
        }

        // bias prefetch (drained by prologue VMCNT0)
        float bias_v[4];
#pragma unroll
        for (int ni = 0; ni < 4; ++ni) {
            int cgl = c0 + wn * 64 + ni * 16 + s;
            bias_v[ni] = (cgl < C) ? bias[cbase + cgl] : 0.f;
        }

        f32x4 acc[4][4];
#pragma unroll
        for (int mi = 0; mi < 4; ++mi)
#pragma unroll
            for (int ni = 0; ni < 4; ++ni) acc[mi][ni] = (f32x4)0.f;

        // ---- prologue: stage k=0 into buf0, full drain.
        // (The s_barrier here also separates this ctile's As0/Bs0 writes from
        //  the previous ctile's tail readers in other waves.)
        STAGE(As0, Bs0, 0);
        VMCNT0();
        BAR();

        // ---- steady state: 15 pairs = K-steps k = 0..928 (pairs of 32)
        int k = 0;
        for (int kp = 0; kp < 15; ++kp) {
            STAGE(As1, Bs1, k + 32);
            VMCNT4();                 // retire buf0's 4; buf1's 4 stay in flight
            BAR();
            MFMA_STEP(As0, Bs0);      // k
            BAR();                    // buf0 readers done -> reusable

            STAGE(As0, Bs0, k + 64);
            VMCNT4();                 // retire buf1's 4; buf0's 4 stay in flight
            BAR();
            MFMA_STEP(As1, Bs1);      // k+32
            BAR();                    // buf1 readers done -> reusable
            k += 64;
        }

        // ---- tail: k = 960 (buf0), 992 (buf1)
        STAGE(As1, Bs1, 992);
        VMCNT4();
        BAR();
        MFMA_STEP(As0, Bs0);          // k = 960
        BAR();                        // protects As0/Bs0 for next ctile's prologue
        VMCNT0();                     // certify buf1's final stage
        BAR();
        MFMA_STEP(As1, Bs1);          // k = 992

        // ---- per-ctile epilogue: C/D layout col = lane&15 (=s), row = q*4+reg
        // (acc + lane-private part[] only; As1/Bs1 not re-staged until after
        //  the next ctile's prologue barrier)
#pragma unroll
        for (int mi = 0; mi < 4; ++mi) {
#pragma unroll
            for (int r = 0; r < 4; ++r) {
                int rl   = wm * 64 + mi * 16 + q * 4 + r;
                int orig = orig_s[rl];
                int tg   = tgt_s[rl];
                float sum = 0.f;
#pragma unroll
                for (int ni = 0; ni < 4; ++ni) {
                    int cgl = c0 + wn * 64 + ni * 16 + s;
                    float logit = acc[mi][ni][r] + bias_v[ni];
                    bool valid = (cgl < C) && (orig >= 0);
                    float e = valid ? __expf(logit) : 0.f;
                    sum += e;
                    if (valid && (cbase + cgl == tg)) capture[orig] = logit;
                }
                sum += __shfl_xor(sum, 1, 64);
                sum += __shfl_xor(sum, 2, 64);
                sum += __shfl_xor(sum, 4, 64);
                sum += __shfl_xor(sum, 8, 64);
                if (s == 0 && orig >= 0) part[wn * 128 + rl] += sum;  // lane-owned slot
            }
        }
    }

#undef STAGE
#undef MFMA_STEP

    // ---- merge wave halves, one atomic per row per block
    __syncthreads();
    if (tid < 128) {
        int orig = orig_s[tid];
        if (orig >= 0) {
            float tot = part[tid] + part[128 + tid];
            atomicAdd(&sumexp[orig], tot);
        }
    }
}

// ---------------------------------------------------------------------------
// FALLBACK PATH (fp32 staging) -- used if ws too small
// ---------------------------------------------------------------------------
__launch_bounds__(256)
__global__ void gemm_lse_k(const float* __restrict__ input,
                           const float* __restrict__ weight,
                           const float* __restrict__ bias,
                           const int*   __restrict__ target,
                           const int*   __restrict__ rowlist,
                           const int*   __restrict__ cnt_ptr,
                           int fixed_cnt,
                           int class_base, int C,
                           float* __restrict__ sumexp,
                           float* __restrict__ capture)
{
    const int cnt = cnt_ptr ? *cnt_ptr : fixed_cnt;
    const int r0  = blockIdx.x * 128;
    if (r0 >= cnt) return;
    const int c0  = blockIdx.y * 128;

    __shared__ unsigned short As[128 * 40];
    __shared__ unsigned short Bs[128 * 40];
    __shared__ int   orig_s[128];
    __shared__ int   tgt_s[128];
    __shared__ float bias_s[128];

    const int tid = threadIdx.x;
    if (tid < 128) {
        int idx  = r0 + tid;
        int orig = -1;
        if (idx < cnt) orig = rowlist ? rowlist[idx] : idx;
        orig_s[tid] = orig;
        tgt_s[tid]  = (orig >= 0) ? target[orig] : -1;
        int c = c0 + tid;
        bias_s[tid] = (c < C) ? bias[class_base + c] : 0.f;
    }

    const int lane = tid & 63;
    const int wave = tid >> 6;
    const int wm = wave >> 1, wn = wave & 1;
    const int q = lane >> 4, s = lane & 15;

    int aoff[4], boff[4];
#pragma unroll
    for (int i = 0; i < 4; ++i) {
        aoff[i] = (wm * 64 + i * 16 + s) * 40 + q * 8;
        boff[i] = (wn * 64 + i * 16 + s) * 40 + q * 8;
    }

    f32x4 acc[4][4];
#pragma unroll
    for (int mi = 0; mi < 4; ++mi)
#pragma unroll
        for (int ni = 0; ni < 4; ++ni) acc[mi][ni] = (f32x4)0.f;

    for (int k0 = 0; k0 < IN_F; k0 += 32) {
        __syncthreads();
#pragma unroll
        for (int i = 0; i < 2; ++i) {
            int sg  = tid + i * 256;
            int row = sg >> 2;
            int sk  = (sg & 3) << 3;
            {
                int orig = orig_s[row];
                float v[8];
                if (orig >= 0) {
                    const float* p = input + (size_t)orig * IN_F + k0 + sk;
                    f32x4 x0 = *(const f32x4*)p;
                    f32x4 x1 = *(const f32x4*)(p + 4);
                    v[0]=x0[0]; v[1]=x0[1]; v[2]=x0[2]; v[3]=x0[3];
                    v[4]=x1[0]; v[5]=x1[1]; v[6]=x1[2]; v[7]=x1[3];
                } else {
#pragma unroll
                    for (int j = 0; j < 8; ++j) v[j] = 0.f;
                }
                us8 o;
#pragma unroll
                for (int j = 0; j < 8; ++j) o[j] = f2bf(v[j]);
                *(us8*)&As[row * 40 + sk] = o;
            }
            {
                int c = c0 + row;
                float v[8];
                if (c < C) {
                    const float* p = weight + (size_t)(class_base + c) * IN_F + k0 + sk;
                    f32x4 x0 = *(const f32x4*)p;
                    f32x4 x1 = *(const f32x4*)(p + 4);
                    v[0]=x0[0]; v[1]=x0[1]; v[2]=x0[2]; v[3]=x0[3];
                    v[4]=x1[0]; v[5]=x1[1]; v[6]=x1[2]; v[7]=x1[3];
                } else {
#pragma unroll
                    for (int j = 0; j < 8; ++j) v[j] = 0.f;
                }
                us8 o;
#pragma unroll
                for (int j = 0; j < 8; ++j) o[j] = f2bf(v[j]);
                *(us8*)&Bs[row * 40 + sk] = o;
            }
        }
        __syncthreads();

        bf16x8 av[4], bv[4];
#pragma unroll
        for (int i = 0; i < 4; ++i) {
            av[i] = *(const bf16x8*)&As[aoff[i]];
            bv[i] = *(const bf16x8*)&Bs[boff[i]];
        }
#pragma unroll
        for (int mi = 0; mi < 4; ++mi)
#pragma unroll
            for (int ni = 0; ni < 4; ++ni)
                acc[mi][ni] = __builtin_amdgcn_mfma_f32_16x16x32_bf16(
                    av[mi], bv[ni], acc[mi][ni], 0, 0, 0);
    }

#pragma unroll
    for (int mi = 0; mi < 4; ++mi) {
#pragma unroll
        for (int r = 0; r < 4; ++r) {
            int rl   = wm * 64 + mi * 16 + q * 4 + r;
            int orig = orig_s[rl];
            int tg   = tgt_s[rl];
            float sum = 0.f;
#pragma unroll
            for (int ni = 0; ni < 4; ++ni) {
                int cl = wn * 64 + ni * 16 + s;
                int cg = c0 + cl;
                float logit = acc[mi][ni][r] + bias_s[cl];
                bool valid = (cg < C) && (orig >= 0);
                float e = valid ? __expf(logit) : 0.f;
                sum += e;
                if (valid && (class_base + cg == tg)) capture[orig] = logit;
            }
            sum += __shfl_xor(sum, 1, 64);
            sum += __shfl_xor(sum, 2, 64);
            sum += __shfl_xor(sum, 4, 64);
            sum += __shfl_xor(sum, 8, 64);
            if (s == 0 && orig >= 0) atomicAdd(&sumexp[orig], sum);
        }
    }
}

// ---------------------------------------------------------------------------
// Combine: tail-vector logits (2 dots/row, fp32), assemble output, loss accum
// ---------------------------------------------------------------------------
__global__ void combine_k(const float* __restrict__ input,
                          const int*   __restrict__ target,
                          const float* __restrict__ tv,
                          const float* __restrict__ tb,
                          const float* __restrict__ sumexp_head,
                          const float* __restrict__ sumexp_tail,
                          const float* __restrict__ capture,
                          float* __restrict__ out,
                          float* __restrict__ loss_accum)
{
    const int wave = threadIdx.x >> 6, lane = threadIdx.x & 63;
    const int row = blockIdx.x * 4 + wave;
    if (row >= NROWS) return;

    const float* x  = input + (size_t)row * IN_F + lane * 16;
    const float* p0 = tv + lane * 16;
    const float* p1 = tv + IN_F + lane * 16;
    float d0 = 0.f, d1 = 0.f;
#pragma unroll
    for (int i = 0; i < 16; i += 4) {
        f32x4 xv = *(const f32x4*)(x  + i);
        f32x4 a  = *(const f32x4*)(p0 + i);
        f32x4 b  = *(const f32x4*)(p1 + i);
        d0 += xv[0]*a[0] + xv[1]*a[1] + xv[2]*a[2] + xv[3]*a[3];
        d1 += xv[0]*b[0] + xv[1]*b[1] + xv[2]*b[2] + xv[3]*b[3];
    }
#pragma unroll
    for (int m = 32; m; m >>= 1) {
        d0 += __shfl_xor(d0, m, 64);
        d1 += __shfl_xor(d1, m, 64);
    }
    if (lane == 0) {
        float t0 = d0 + tb[0];
        float t1 = d1 + tb[1];
        int tg  = target[row];
        int cid = (tg < C1_LO) ? 0 : ((tg < C1_HI) ? 1 : 2);
        float se_head  = sumexp_head[row] + __expf(t0) + __expf(t1);
        float lse_head = __logf(se_head);
        float head_num = (cid == 0) ? capture[row] : ((cid == 1) ? t0 : t1);
        float o = head_num - lse_head;
        if (cid != 0) o += capture[row] - __logf(sumexp_tail[row]);
        out[row] = o;
        atomicAdd(loss_accum, o);
    }
}

__global__ void finalize_k(const float* __restrict__ loss_accum, float* __restrict__ out) {
    out[NROWS] = -loss_accum[0] * (1.0f / NROWS);
}

// ---------------------------------------------------------------------------
extern "C" void kernel_launch(void* const* d_in, const int* in_sizes, int n_in,
                              void* d_out, int out_size, void* d_ws, size_t ws_size,
                              hipStream_t stream) {
    const float* input  = (const float*)d_in[0];
    const int*   target = (const int*)  d_in[1];
    const float* weight = (const float*)d_in[2];
    const float* bias   = (const float*)d_in[3];
    const float* tv     = (const float*)d_in[4];
    const float* tb     = (const float*)d_in[5];
    float* out = (float*)d_out;
    int*   wsI = (int*)d_ws;
    float* wsF = (float*)d_ws;

    init_ws_k<<<dim3((WS_WORDS + 255) / 256), 256, 0, stream>>>(wsI);
    compact_rows_k<<<dim3(NROWS / 256), 256, 0, stream>>>(target, wsI);

    const bool fast = ws_size >= (size_t)WS_NEEDED;

    if (fast) {
        ushort_t* Wbf = (ushort_t*)((char*)d_ws + WBF_OFF);
        ushort_t* Xbf = (ushort_t*)((char*)d_ws + XBF_OFF);

        convert_bf16_k<<<dim3((WCHUNKS + XCHUNKS + 255) / 256), 256, 0, stream>>>(
            weight, Wbf, input, Xbf);

        gemm_lse_fused_k<<<dim3(GRID_ALL), 256, 0, stream>>>(
            Xbf, Wbf, bias, target, wsI, wsF);
    } else {
        gemm_lse_k<<<dim3(NROWS / 128, (SHORTLIST + 127) / 128), 256, 0, stream>>>(
            input, weight, bias, target,
            nullptr, nullptr, NROWS,
            0, SHORTLIST,
            wsF + WS_SEH, wsF + WS_CAP);
        gemm_lse_k<<<dim3(NROWS / 128, (C1_HI - C1_LO + 127) / 128), 256, 0, stream>>>(
            input, weight, bias, target,
            wsI + WS_RL1, wsI + WS_CNT1, 0,
            C1_LO, C1_HI - C1_LO,
            wsF + WS_SET, wsF + WS_CAP);
        gemm_lse_k<<<dim3(NROWS / 128, (C2_HI - C1_HI + 127) / 128), 256, 0, stream>>>(
            input, weight, bias, target,
            wsI + WS_RL2, wsI + WS_CNT2, 0,
            C1_HI, C2_HI - C1_HI,
            wsF + WS_SET, wsF + WS_CAP);
    }

    combine_k<<<dim3(NROWS / 4), 256, 0, stream>>>(
        input, target, tv, tb,
        wsF + WS_SEH, wsF + WS_SET, wsF + WS_CAP,
        out, wsF + WS_LOSS);

    finalize_k<<<1, 1, 0, stream>>>(wsF + WS_LOSS, out);
}

// Round 6
// 1198.885 us; speedup vs baseline: 1.0008x; 1.0008x over previous
//
#include <hip/hip_runtime.h>
#include <stddef.h>
#include <stdint.h>

// Problem constants
#define IN_F      1024
#define SHORTLIST 4000
#define C1_LO     4000
#define C1_HI     20000
#define C2_HI     50257
#define NROWS     8192

// Workspace layout (4-byte words) -- bookkeeping region
#define WS_CNT1   0
#define WS_CNT2   1
#define WS_LOSS   2
#define WS_RL1    4
#define WS_RL2    (4 + 8192)
#define WS_SEH    (4 + 2*8192)            // sumexp_head[8192]
#define WS_SET    (WS_SEH + 8192)         // sumexp_tail[8192]
#define WS_CAP    (WS_SET + 8192)         // captured target/gather logit[8192]
#define WS_WORDS  (WS_CAP + 8192)         // ~164 KB

// bf16 scratch region (bytes)
#define WBF_OFF   (262144)                              // 256 KB aligned
#define XBF_OFF   (WBF_OFF + 103219200)                 // padded/aligned
#define XBF_BYTES ((size_t)NROWS * IN_F * 2)            // 16,777,216
#define WS_NEEDED (XBF_OFF + XBF_BYTES)

// Fused-GEMM grid: jobs concatenated, row-strip (of 128) fastest for B L2 reuse.
// Each block covers 4 column-tiles of 128 => 512 classes.
#define GRID_HEAD 512          // 64 rowstrips x 8  cgroups (4000 cls -> 32 strips)
#define GRID_T1   2048         // 64 rowstrips x 32 cgroups (16000 -> 125 strips)
#define GRID_T2   3840         // 64 rowstrips x 60 cgroups (30257 -> 237 strips)
#define GRID_ALL  (GRID_HEAD + GRID_T1 + GRID_T2)

typedef float          f32x4  __attribute__((ext_vector_type(4)));
typedef __bf16         bf16x8 __attribute__((ext_vector_type(8)));
typedef unsigned short us8    __attribute__((ext_vector_type(8)));
typedef unsigned short ushort_t;

__device__ __forceinline__ unsigned short f2bf(float f) {
    unsigned int u = __float_as_uint(f);
    u += 0x7fffu + ((u >> 16) & 1u);   // round-to-nearest-even
    return (unsigned short)(u >> 16);
}

__device__ __forceinline__ void gl_lds16(const void* g, void* l) {
    __builtin_amdgcn_global_load_lds(
        (const __attribute__((address_space(1))) void*)g,
        (__attribute__((address_space(3))) void*)l, 16, 0, 0);
}

#define VMCNT4() asm volatile("s_waitcnt vmcnt(4)" ::: "memory")
#define VMCNT0() asm volatile("s_waitcnt vmcnt(0)" ::: "memory")
#define BAR()    __builtin_amdgcn_s_barrier()

// ---------------------------------------------------------------------------
__global__ void init_ws_k(int* __restrict__ ws) {
    int i = blockIdx.x * 256 + threadIdx.x;
    if (i < WS_WORDS) {
        int v = (i >= WS_RL1 && i < WS_RL1 + 2*8192) ? -1 : 0;
        ws[i] = v;
    }
}

__global__ void compact_rows_k(const int* __restrict__ target, int* __restrict__ ws) {
    int row = blockIdx.x * 256 + threadIdx.x;
    if (row >= NROWS) return;
    int tg = target[row];
    if (tg >= C1_LO) {
        if (tg < C1_HI) {
            int p = atomicAdd(&ws[WS_CNT1], 1);
            ws[WS_RL1 + p] = row;
        } else {
            int p = atomicAdd(&ws[WS_CNT2], 1);
            ws[WS_RL2 + p] = row;
        }
    }
}

// ---------------------------------------------------------------------------
// fp32 -> bf16 bulk convert: weight then input in one dispatch
// ---------------------------------------------------------------------------
#define WCHUNKS ((C2_HI * IN_F) / 8)       // 6,432,896
#define XCHUNKS ((NROWS * IN_F) / 8)       // 1,048,576
__global__ void convert_bf16_k(const float* __restrict__ w_src,
                               ushort_t* __restrict__ w_dst,
                               const float* __restrict__ x_src,
                               ushort_t* __restrict__ x_dst) {
    int i = blockIdx.x * 256 + threadIdx.x;
    const float* p;
    ushort_t* d;
    if (i < WCHUNKS) { p = w_src + (size_t)i * 8; d = w_dst + (size_t)i * 8; }
    else {
        int j = i - WCHUNKS;
        if (j >= XCHUNKS) return;
        p = x_src + (size_t)j * 8; d = x_dst + (size_t)j * 8;
    }
    f32x4 x0 = *(const f32x4*)p;
    f32x4 x1 = *(const f32x4*)(p + 4);
    us8 o;
    o[0] = f2bf(x0[0]); o[1] = f2bf(x0[1]); o[2] = f2bf(x0[2]); o[3] = f2bf(x0[3]);
    o[4] = f2bf(x1[0]); o[5] = f2bf(x1[1]); o[6] = f2bf(x1[2]); o[7] = f2bf(x1[3]);
    *(us8*)d = o;
}

// ---------------------------------------------------------------------------
// FUSED bf16 GEMM + exp-sum + target capture, all 3 cluster jobs in one grid.
// 128x128 tile, gl_lds(16B) staging, BK=32.
//
// THIS REVISION: TRIPLE-buffered (As0/1/2, Bs0/1/2 -- static names, rule #20),
// ONE barrier per K-window, depth-2 prefetch. Phase:
//     s_waitcnt vmcnt(4)      // retire buf(w)'s 4 loads (staged 2 phases ago)
//     s_barrier               // all waves certified buf(w); readers of
//                             // buf(w+2)'s OLD data have completed their
//                             // ds_reads (MFMA data-deps force lgkm waits
//                             // before the wave can reach this barrier)
//     STAGE(buf(w+2), k+64)   // writes AFTER the barrier -> WAR-safe
//     MFMA(buf(w))
// vmcnt ledger: steady outstanding = 8 (two buffers in flight); vmcnt(4)
// always retires the oldest 4 = the buffer about to be read. Extraneous
// vmem ops (bias prefetch, rare capture stores) are always OLDER than the
// certified buffer, so count-based retirement stays safe for any compiler
// ordering. vmcnt(0) only at the ctile tail. Barriers/ctile: 33 (round-3
// level) with depth-2 latency cover (round-5 paid 64 barriers for depth-1
// -> neutral; this keeps the cover, drops the cost).
// LDS = 6 x 8KB + 2KB = 50KB -> 3 blocks/CU preserved.
//
// Layout (verified in round-5, SQ_LDS_BANK_CONFLICT=0, passed):
//   stage: inst t = wave*2+i covers rows t*16..t*16+15; lane l -> row
//          t*16+(l>>2), LDS slot l&3, global k-quarter psw = (l&3)^((l>>3)&3)
//   read : row r, k-octet q -> slot q ^ ((s>>1)&3)
// Fragment mapping and K-accumulation order identical to rounds 3/5.
// ---------------------------------------------------------------------------
__launch_bounds__(256, 3)
__global__ void gemm_lse_fused_k(const ushort_t* __restrict__ Xbf,  // [NROWS][IN_F]
                                 const ushort_t* __restrict__ Wbf,  // [C2_HI][IN_F]
                                 const float* __restrict__ bias,
                                 const int*   __restrict__ target,
                                 int*   __restrict__ wsI,
                                 float* __restrict__ wsF)
{
    // ---- job decode (row-strip fastest within each job)
    const int bid = blockIdx.x;
    int rs, cg, cbase, C, cnt;
    const int* rowlist;           // null => identity
    float* sumexp;
    if (bid < GRID_HEAD) {
        rs = bid & 63; cg = bid >> 6;
        cbase = 0; C = SHORTLIST; rowlist = nullptr; cnt = NROWS;
        sumexp = wsF + WS_SEH;
    } else if (bid < GRID_HEAD + GRID_T1) {
        int b = bid - GRID_HEAD;
        rs = b & 63; cg = b >> 6;
        cbase = C1_LO; C = C1_HI - C1_LO; rowlist = wsI + WS_RL1; cnt = wsI[WS_CNT1];
        sumexp = wsF + WS_SET;
    } else {
        int b = bid - (GRID_HEAD + GRID_T1);
        rs = b & 63; cg = b >> 6;
        cbase = C1_HI; C = C2_HI - C1_HI; rowlist = wsI + WS_RL2; cnt = wsI[WS_CNT2];
        sumexp = wsF + WS_SET;
    }
    const int r0 = rs * 128;
    if (r0 >= cnt) return;
    float* capture = wsF + WS_CAP;

    __shared__ ushort_t As0[128 * 32];   // 8 KB each
    __shared__ ushort_t Bs0[128 * 32];
    __shared__ ushort_t As1[128 * 32];
    __shared__ ushort_t Bs1[128 * 32];
    __shared__ ushort_t As2[128 * 32];
    __shared__ ushort_t Bs2[128 * 32];
    __shared__ int   orig_s[128];
    __shared__ int   tgt_s[128];
    __shared__ float part[256];          // [wn][row] exp-sum accum across ctiles

    const int tid = threadIdx.x;
    part[tid] = 0.f;
    if (tid < 128) {
        int idx  = r0 + tid;
        int orig = (idx < cnt) ? (rowlist ? rowlist[idx] : idx) : -1;
        orig_s[tid] = orig;
        tgt_s[tid]  = (orig >= 0) ? target[orig] : -1;
    }
    __syncthreads();

    const int lane = tid & 63;
    const int wave = tid >> 6;
    const int wm = wave >> 1, wn = wave & 1;
    const int q = lane >> 4, s = lane & 15;

    // ---- staging setup: wave handles insts t = wave*2+i (i=0,1), each inst
    // covers rows t*16..t*16+15. lane l -> row t*16+(l>>2), LDS slot l&3;
    // source k-quarter pre-swizzled: psw = (l&3) ^ ((l>>3)&3).
    const int lrow = lane >> 2;                    // row within 16
    const int psw  = (lane & 3) ^ ((lane >> 3) & 3);
    const ushort_t* aptr[2];
    int tsl[2];                                     // wave-uniform LDS inst base
    int brow[2];
#pragma unroll
    for (int i = 0; i < 2; ++i) {
        int t  = wave * 2 + i;
        int rt = t * 16 + lrow;
        int orig = orig_s[rt]; if (orig < 0) orig = 0;          // safe addr; masked later
        aptr[i] = Xbf + (size_t)orig * IN_F + psw * 8;
        tsl[i]  = t * 512;                                      // 512 ushorts = 1KB
        brow[i] = rt;
    }

    // ---- fragment read offsets (ushort units): row*32 + (q^((s>>1)&3))*8
    int ar_off[4], br_off[4];
#pragma unroll
    for (int i = 0; i < 4; ++i) {
        ar_off[i] = (wm * 64 + i * 16 + s) * 32 + (q ^ ((s >> 1) & 3)) * 8;
        br_off[i] = (wn * 64 + i * 16 + s) * 32 + (q ^ ((s >> 1) & 3)) * 8;
    }

#define STAGE(AS, BS, K0) do {                                                 \
    _Pragma("unroll")                                                          \
    for (int i_ = 0; i_ < 2; ++i_) {                                           \
        gl_lds16(aptr[i_] + (K0), &AS[tsl[i_]]);                               \
        gl_lds16(bptr[i_] + (K0), &BS[tsl[i_]]);                               \
    }                                                                          \
} while (0)

#define MFMA_STEP(AS, BS) do {                                                 \
    bf16x8 av_[4], bv_[4];                                                     \
    _Pragma("unroll")                                                          \
    for (int i_ = 0; i_ < 4; ++i_) {                                           \
        av_[i_] = *(const bf16x8*)&AS[ar_off[i_]];                             \
        bv_[i_] = *(const bf16x8*)&BS[br_off[i_]];                             \
    }                                                                          \
    _Pragma("unroll")                                                          \
    for (int mi_ = 0; mi_ < 4; ++mi_)                                          \
        _Pragma("unroll")                                                      \
        for (int ni_ = 0; ni_ < 4; ++ni_)                                      \
            acc[mi_][ni_] = __builtin_amdgcn_mfma_f32_16x16x32_bf16(           \
                av_[mi_], bv_[ni_], acc[mi_][ni_], 0, 0, 0);                   \
} while (0)

    // ---- loop over 4 column-tiles
    for (int ct = 0; ct < 4; ++ct) {
        const int c0 = (cg * 4 + ct) * 128;
        if (c0 >= C) break;                     // block-uniform

        const ushort_t* bptr[2];
#pragma unroll
        for (int i = 0; i < 2; ++i) {
            int c = c0 + brow[i]; if (c >= C) c = C - 1;    // clamp; masked later
            bptr[i] = Wbf + (size_t)(cbase + c) * IN_F + psw * 8;
        }

        // bias prefetch: older than all stages -> retired by early vmcnt(4)s
        float bias_v[4];
#pragma unroll
        for (int ni = 0; ni < 4; ++ni) {
            int cgl = c0 + wn * 64 + ni * 16 + s;
            bias_v[ni] = (cgl < C) ? bias[cbase + cgl] : 0.f;
        }

        f32x4 acc[4][4];
#pragma unroll
        for (int mi = 0; mi < 4; ++mi)
#pragma unroll
            for (int ni = 0; ni < 4; ++ni) acc[mi][ni] = (f32x4)0.f;

        // ---- ctile prologue: barrier separates prev ctile's tail readers
        // (and epilogue) from this ctile's buffer writes; then prime 2 deep.
        BAR();
        STAGE(As0, Bs0, 0);        // outstanding 4
        STAGE(As1, Bs1, 32);       // outstanding 8

        // ---- steady state: windows 0..29 in 10 triple-phases
        int k = 0;
        for (int j = 0; j < 10; ++j) {
            VMCNT4(); BAR(); STAGE(As2, Bs2, k + 64);  MFMA_STEP(As0, Bs0);  // k
            VMCNT4(); BAR(); STAGE(As0, Bs0, k + 96);  MFMA_STEP(As1, Bs1);  // k+32
            VMCNT4(); BAR(); STAGE(As1, Bs1, k + 128); MFMA_STEP(As2, Bs2);  // k+64
            k += 96;
        }
        // k == 960: As0 holds 960, As1 holds 992 (staged in j=9), out = 8
        VMCNT4(); BAR(); MFMA_STEP(As0, Bs0);   // k = 960, out -> 4
        VMCNT0(); BAR(); MFMA_STEP(As1, Bs1);   // k = 992, out -> 0

        // ---- per-ctile epilogue: C/D layout col = lane&15 (=s), row = q*4+reg
        // register + part[] (disjoint LDS) only; next ctile's prologue BAR
        // separates us from buffer re-staging.
#pragma unroll
        for (int mi = 0; mi < 4; ++mi) {
#pragma unroll
            for (int r = 0; r < 4; ++r) {
                int rl   = wm * 64 + mi * 16 + q * 4 + r;
                int orig = orig_s[rl];
                int tg   = tgt_s[rl];
                float sum = 0.f;
#pragma unroll
                for (int ni = 0; ni < 4; ++ni) {
                    int cgl = c0 + wn * 64 + ni * 16 + s;
                    float logit = acc[mi][ni][r] + bias_v[ni];
                    bool valid = (cgl < C) && (orig >= 0);
                    float e = valid ? __expf(logit) : 0.f;
                    sum += e;
                    if (valid && (cbase + cgl == tg)) capture[orig] = logit;
                }
                sum += __shfl_xor(sum, 1, 64);
                sum += __shfl_xor(sum, 2, 64);
                sum += __shfl_xor(sum, 4, 64);
                sum += __shfl_xor(sum, 8, 64);
                if (s == 0 && orig >= 0) part[wn * 128 + rl] += sum;  // lane-owned slot
            }
        }
    }

#undef STAGE
#undef MFMA_STEP

    // ---- merge wave halves, one atomic per row per block
    __syncthreads();
    if (tid < 128) {
        int orig = orig_s[tid];
        if (orig >= 0) {
            float tot = part[tid] + part[128 + tid];
            atomicAdd(&sumexp[orig], tot);
        }
    }
}

// ---------------------------------------------------------------------------
// FALLBACK PATH (fp32 staging) -- used if ws too small
// ---------------------------------------------------------------------------
__launch_bounds__(256)
__global__ void gemm_lse_k(const float* __restrict__ input,
                           const float* __restrict__ weight,
                           const float* __restrict__ bias,
                           const int*   __restrict__ target,
                           const int*   __restrict__ rowlist,
                           const int*   __restrict__ cnt_ptr,
                           int fixed_cnt,
                           int class_base, int C,
                           float* __restrict__ sumexp,
                           float* __restrict__ capture)
{
    const int cnt = cnt_ptr ? *cnt_ptr : fixed_cnt;
    const int r0  = blockIdx.x * 128;
    if (r0 >= cnt) return;
    const int c0  = blockIdx.y * 128;

    __shared__ unsigned short As[128 * 40];
    __shared__ unsigned short Bs[128 * 40];
    __shared__ int   orig_s[128];
    __shared__ int   tgt_s[128];
    __shared__ float bias_s[128];

    const int tid = threadIdx.x;
    if (tid < 128) {
        int idx  = r0 + tid;
        int orig = -1;
        if (idx < cnt) orig = rowlist ? rowlist[idx] : idx;
        orig_s[tid] = orig;
        tgt_s[tid]  = (orig >= 0) ? target[orig] : -1;
        int c = c0 + tid;
        bias_s[tid] = (c < C) ? bias[class_base + c] : 0.f;
    }

    const int lane = tid & 63;
    const int wave = tid >> 6;
    const int wm = wave >> 1, wn = wave & 1;
    const int q = lane >> 4, s = lane & 15;

    int aoff[4], boff[4];
#pragma unroll
    for (int i = 0; i < 4; ++i) {
        aoff[i] = (wm * 64 + i * 16 + s) * 40 + q * 8;
        boff[i] = (wn * 64 + i * 16 + s) * 40 + q * 8;
    }

    f32x4 acc[4][4];
#pragma unroll
    for (int mi = 0; mi < 4; ++mi)
#pragma unroll
        for (int ni = 0; ni < 4; ++ni) acc[mi][ni] = (f32x4)0.f;

    for (int k0 = 0; k0 < IN_F; k0 += 32) {
        __syncthreads();
#pragma unroll
        for (int i = 0; i < 2; ++i) {
            int sg  = tid + i * 256;
            int row = sg >> 2;
            int sk  = (sg & 3) << 3;
            {
                int orig = orig_s[row];
                float v[8];
                if (orig >= 0) {
                    const float* p = input + (size_t)orig * IN_F + k0 + sk;
                    f32x4 x0 = *(const f32x4*)p;
                    f32x4 x1 = *(const f32x4*)(p + 4);
                    v[0]=x0[0]; v[1]=x0[1]; v[2]=x0[2]; v[3]=x0[3];
                    v[4]=x1[0]; v[5]=x1[1]; v[6]=x1[2]; v[7]=x1[3];
                } else {
#pragma unroll
                    for (int j = 0; j < 8; ++j) v[j] = 0.f;
                }
                us8 o;
#pragma unroll
                for (int j = 0; j < 8; ++j) o[j] = f2bf(v[j]);
                *(us8*)&As[row * 40 + sk] = o;
            }
            {
                int c = c0 + row;
                float v[8];
                if (c < C) {
                    const float* p = weight + (size_t)(class_base + c) * IN_F + k0 + sk;
                    f32x4 x0 = *(const f32x4*)p;
                    f32x4 x1 = *(const f32x4*)(p + 4);
                    v[0]=x0[0]; v[1]=x0[1]; v[2]=x0[2]; v[3]=x0[3];
                    v[4]=x1[0]; v[5]=x1[1]; v[6]=x1[2]; v[7]=x1[3];
                } else {
#pragma unroll
                    for (int j = 0; j < 8; ++j) v[j] = 0.f;
                }
                us8 o;
#pragma unroll
                for (int j = 0; j < 8; ++j) o[j] = f2bf(v[j]);
                *(us8*)&Bs[row * 40 + sk] = o;
            }
        }
        __syncthreads();

        bf16x8 av[4], bv[4];
#pragma unroll
        for (int i = 0; i < 4; ++i) {
            av[i] = *(const bf16x8*)&As[aoff[i]];
            bv[i] = *(const bf16x8*)&Bs[boff[i]];
        }
#pragma unroll
        for (int mi = 0; mi < 4; ++mi)
#pragma unroll
            for (int ni = 0; ni < 4; ++ni)
                acc[mi][ni] = __builtin_amdgcn_mfma_f32_16x16x32_bf16(
                    av[mi], bv[ni], acc[mi][ni], 0, 0, 0);
    }

#pragma unroll
    for (int mi = 0; mi < 4; ++mi) {
#pragma unroll
        for (int r = 0; r < 4; ++r) {
            int rl   = wm * 64 + mi * 16 + q * 4 + r;
            int orig = orig_s[rl];
            int tg   = tgt_s[rl];
            float sum = 0.f;
#pragma unroll
            for (int ni = 0; ni < 4; ++ni) {
                int cl = wn * 64 + ni * 16 + s;
                int cg = c0 + cl;
                float logit = acc[mi][ni][r] + bias_s[cl];
                bool valid = (cg < C) && (orig >= 0);
                float e = valid ? __expf(logit) : 0.f;
                sum += e;
                if (valid && (class_base + cg == tg)) capture[orig] = logit;
            }
            sum += __shfl_xor(sum, 1, 64);
            sum += __shfl_xor(sum, 2, 64);
            sum += __shfl_xor(sum, 4, 64);
            sum += __shfl_xor(sum, 8, 64);
            if (s == 0 && orig >= 0) atomicAdd(&sumexp[orig], sum);
        }
    }
}

// ---------------------------------------------------------------------------
// Combine: tail-vector logits (2 dots/row, fp32), assemble output, loss accum
// ---------------------------------------------------------------------------
__global__ void combine_k(const float* __restrict__ input,
                          const int*   __restrict__ target,
                          const float* __restrict__ tv,
                          const float* __restrict__ tb,
                          const float* __restrict__ sumexp_head,
                          const float* __restrict__ sumexp_tail,
                          const float* __restrict__ capture,
                          float* __restrict__ out,
                          float* __restrict__ loss_accum)
{
    const int wave = threadIdx.x >> 6, lane = threadIdx.x & 63;
    const int row = blockIdx.x * 4 + wave;
    if (row >= NROWS) return;

    const float* x  = input + (size_t)row * IN_F + lane * 16;
    const float* p0 = tv + lane * 16;
    const float* p1 = tv + IN_F + lane * 16;
    float d0 = 0.f, d1 = 0.f;
#pragma unroll
    for (int i = 0; i < 16; i += 4) {
        f32x4 xv = *(const f32x4*)(x  + i);
        f32x4 a  = *(const f32x4*)(p0 + i);
        f32x4 b  = *(const f32x4*)(p1 + i);
        d0 += xv[0]*a[0] + xv[1]*a[1] + xv[2]*a[2] + xv[3]*a[3];
        d1 += xv[0]*b[0] + xv[1]*b[1] + xv[2]*b[2] + xv[3]*b[3];
    }
#pragma unroll
    for (int m = 32; m; m >>= 1) {
        d0 += __shfl_xor(d0, m, 64);
        d1 += __shfl_xor(d1, m, 64);
    }
    if (lane == 0) {
        float t0 = d0 + tb[0];
        float t1 = d1 + tb[1];
        int tg  = target[row];
        int cid = (tg < C1_LO) ? 0 : ((tg < C1_HI) ? 1 : 2);
        float se_head  = sumexp_head[row] + __expf(t0) + __expf(t1);
        float lse_head = __logf(se_head);
        float head_num = (cid == 0) ? capture[row] : ((cid == 1) ? t0 : t1);
        float o = head_num - lse_head;
        if (cid != 0) o += capture[row] - __logf(sumexp_tail[row]);
        out[row] = o;
        atomicAdd(loss_accum, o);
    }
}

__global__ void finalize_k(const float* __restrict__ loss_accum, float* __restrict__ out) {
    out[NROWS] = -loss_accum[0] * (1.0f / NROWS);
}

// ---------------------------------------------------------------------------
extern "C" void kernel_launch(void* const* d_in, const int* in_sizes, int n_in,
                              void* d_out, int out_size, void* d_ws, size_t ws_size,
                              hipStream_t stream) {
    const float* input  = (const float*)d_in[0];
    const int*   target = (const int*)  d_in[1];
    const float* weight = (const float*)d_in[2];
    const float* bias   = (const float*)d_in[3];
    const float* tv     = (const float*)d_in[4];
    const float* tb     = (const float*)d_in[5];
    float* out = (float*)d_out;
    int*   wsI = (int*)d_ws;
    float* wsF = (float*)d_ws;

    init_ws_k<<<dim3((WS_WORDS + 255) / 256), 256, 0, stream>>>(wsI);
    compact_rows_k<<<dim3(NROWS / 256), 256, 0, stream>>>(target, wsI);

    const bool fast = ws_size >= (size_t)WS_NEEDED;

    if (fast) {
        ushort_t* Wbf = (ushort_t*)((char*)d_ws + WBF_OFF);
        ushort_t* Xbf = (ushort_t*)((char*)d_ws + XBF_OFF);

        convert_bf16_k<<<dim3((WCHUNKS + XCHUNKS + 255) / 256), 256, 0, stream>>>(
            weight, Wbf, input, Xbf);

        gemm_lse_fused_k<<<dim3(GRID_ALL), 256, 0, stream>>>(
            Xbf, Wbf, bias, target, wsI, wsF);
    } else {
        gemm_lse_k<<<dim3(NROWS / 128, (SHORTLIST + 127) / 128), 256, 0, stream>>>(
            input, weight, bias, target,
            nullptr, nullptr, NROWS,
            0, SHORTLIST,
            wsF + WS_SEH, wsF + WS_CAP);
        gemm_lse_k<<<dim3(NROWS / 128, (C1_HI - C1_LO + 127) / 128), 256, 0, stream>>>(
            input, weight, bias, target,
            wsI + WS_RL1, wsI + WS_CNT1, 0,
            C1_LO, C1_HI - C1_LO,
            wsF + WS_SET, wsF + WS_CAP);
        gemm_lse_k<<<dim3(NROWS / 128, (C2_HI - C1_HI + 127) / 128), 256, 0, stream>>>(
            input, weight, bias, target,
            wsI + WS_RL2, wsI + WS_CNT2, 0,
            C1_HI, C2_HI - C1_HI,
            wsF + WS_SET, wsF + WS_CAP);
    }

    combine_k<<<dim3(NROWS / 4), 256, 0, stream>>>(
        input, target, tv, tb,
        wsF + WS_SEH, wsF + WS_SET, wsF + WS_CAP,
        out, wsF + WS_LOSS);

    finalize_k<<<1, 1, 0, stream>>>(wsF + WS_LOSS, out);
}